// Round 8
// baseline (120.930 us; speedup 1.0000x reference)
//
#include <hip/hip_runtime.h>

#define S_LEN  2048
#define DMODEL 1024
#define NHEAD  16
#define DHEAD  64
#define SCALE_F 0.125f
#define SL2E_F 0.180336880f   // SCALE_F * log2(e)

typedef unsigned short ushort_t;
typedef __attribute__((ext_vector_type(8))) short bf16x8;
typedef __attribute__((ext_vector_type(4))) float f32x4;

typedef __attribute__((address_space(1))) void gv_t;
typedef __attribute__((address_space(3))) void lv_t;

__device__ __forceinline__ ushort_t f2bf(float f) {
    unsigned u = __builtin_bit_cast(unsigned, f);
    unsigned r = (u + 0x7FFFu + ((u >> 16) & 1u)) >> 16;
    return (ushort_t)r;
}

__device__ __forceinline__ unsigned cvtpk_bf16(float a, float b) {
    unsigned r;
    asm("v_cvt_pk_bf16_f32 %0, %1, %2" : "=v"(r) : "v"(a), "v"(b));
    return r;
}

__device__ __forceinline__ void gload16(const ushort_t* g, ushort_t* l) {
    __builtin_amdgcn_global_load_lds((gv_t*)g, (lv_t*)l, 16, 0, 0);
}

template<int N> __device__ __forceinline__ void wait_vmcnt() {
    if constexpr (N == 8)      asm volatile("s_waitcnt vmcnt(8)" ::: "memory");
    else if constexpr (N == 6) asm volatile("s_waitcnt vmcnt(6)" ::: "memory");
    else if constexpr (N == 4) asm volatile("s_waitcnt vmcnt(4)" ::: "memory");
    else                       asm volatile("s_waitcnt vmcnt(0)" ::: "memory");
}

// Cast x, Wq, Wk, Wv, Wo (f32) into one contiguous bf16 region.
__global__ void cast_all(const float* __restrict__ x,
                         const float* __restrict__ Wq, const float* __restrict__ Wk,
                         const float* __restrict__ Wv, const float* __restrict__ Wo,
                         ushort_t* __restrict__ dst, int n4) {
    int i = blockIdx.x * blockDim.x + threadIdx.x;
    int stride = gridDim.x * blockDim.x;
    for (int idx = i; idx < n4; idx += stride) {
        const float* src; int off;
        if (idx < 1048576)      { src = x;  off = idx; }
        else if (idx < 1310720) { src = Wq; off = idx - 1048576; }
        else if (idx < 1572864) { src = Wk; off = idx - 1310720; }
        else if (idx < 1835008) { src = Wv; off = idx - 1572864; }
        else                    { src = Wo; off = idx - 1835008; }
        float4 f = ((const float4*)src)[off];
        ushort4 o;
        o.x = f2bf(f.x); o.y = f2bf(f.y); o.z = f2bf(f.z); o.w = f2bf(f.w);
        ((ushort4*)dst)[idx] = o;
    }
}

// C = A @ B^T + bias.  BK=64, XOR-swizzled LDS (both-sides), 2-deep pipeline
// with counted vmcnt + raw barriers (loads stay in flight across barriers).
// MODE 0 (BM=128): fused QKV epilogue, N=3072; Q scaled by SL2E.
// MODE 2 (BM=64): out0 = f32 flat [M][N].
template<int MODE, int BM>
__launch_bounds__(256)
__global__ void gemm_bt(const ushort_t* __restrict__ A, const ushort_t* __restrict__ Bw,
                        const float* __restrict__ b0, const float* __restrict__ b1,
                        const float* __restrict__ b2,
                        void* __restrict__ out0, void* __restrict__ out1, void* __restrict__ out2,
                        int M, int N, int K) {
    constexpr int MF = BM / 32;
    constexpr int NLOADS = BM / 32 + 4;          // per-wave gloads per K-step
    __shared__ ushort_t As[2][BM][64];
    __shared__ ushort_t Bs[2][128][64];
    const int tid  = threadIdx.x;
    const int lane = tid & 63;
    const int w    = tid >> 6;
    const int wr   = w >> 1, wc = w & 1;
    const int m0   = blockIdx.x * BM;
    const int n0   = blockIdx.y * 128;
    const int l15  = lane & 15;
    const int lg   = lane >> 4;
    const int srow8 = lane >> 3;                 // 0..7 within 8-row group
    const int scol8 = ((lane & 7) ^ srow8) * 8;  // source-side XOR swizzle

    f32x4 acc[MF][4] = {};

    auto stage = [&](int buf, int k0) {
#pragma unroll
        for (int j = 0; j < BM / 32; j++) {      // A: BM/8 row-groups over 4 waves
            const int rg = (w * (BM / 32) + j) * 8;
            gload16(A + (size_t)(m0 + rg + srow8) * K + k0 + scol8, &As[buf][rg][0]);
        }
#pragma unroll
        for (int j = 0; j < 4; j++) {            // B: 16 row-groups over 4 waves
            const int rg = (w * 4 + j) * 8;
            gload16(Bw + (size_t)(n0 + rg + srow8) * K + k0 + scol8, &Bs[buf][rg][0]);
        }
    };

    stage(0, 0);
    int buf = 0;

    for (int k0 = 0; k0 < K; k0 += 64) {
        if (k0 + 64 < K) {
            stage(buf ^ 1, k0 + 64);             // prefetch next tile
            wait_vmcnt<NLOADS>();                // only current tile's loads done
        } else {
            wait_vmcnt<0>();
        }
        __builtin_amdgcn_s_barrier();
        __builtin_amdgcn_sched_barrier(0);

        bf16x8 af[MF][2], bfr[4][2];
#pragma unroll
        for (int i = 0; i < MF; i++) {
            const int row = wr * (BM / 2) + i * 16 + l15;
#pragma unroll
            for (int kk = 0; kk < 2; kk++)
                af[i][kk] = *(const bf16x8*)&As[buf][row][((kk*4 + lg) ^ (l15 & 7)) * 8];
        }
#pragma unroll
        for (int i = 0; i < 4; i++) {
            const int row = wc * 64 + i * 16 + l15;
#pragma unroll
            for (int kk = 0; kk < 2; kk++)
                bfr[i][kk] = *(const bf16x8*)&Bs[buf][row][((kk*4 + lg) ^ (l15 & 7)) * 8];
        }
        __builtin_amdgcn_s_setprio(1);
#pragma unroll
        for (int kk = 0; kk < 2; kk++)
#pragma unroll
            for (int mf = 0; mf < MF; mf++)
#pragma unroll
                for (int nf = 0; nf < 4; nf++)
                    acc[mf][nf] = __builtin_amdgcn_mfma_f32_16x16x32_bf16(af[mf][kk], bfr[nf][kk], acc[mf][nf], 0, 0, 0);
        __builtin_amdgcn_s_setprio(0);

        asm volatile("s_waitcnt lgkmcnt(0)" ::: "memory");
        __builtin_amdgcn_sched_barrier(0);
        __builtin_amdgcn_s_barrier();            // all waves done reading buf
        buf ^= 1;
    }

#pragma unroll
    for (int mf = 0; mf < MF; mf++) {
#pragma unroll
        for (int nf = 0; nf < 4; nf++) {
            const int col = n0 + wc*64 + nf*16 + l15;
            if constexpr (MODE == 2) {
                const float bv = b0[col];
#pragma unroll
                for (int r = 0; r < 4; r++) {
                    const int row = m0 + wr*(BM/2) + mf*16 + lg*4 + r;
                    ((float*)out0)[(size_t)row * N + col] = acc[mf][nf][r] + bv;
                }
            } else {
                const int mat = col >> 10;
                const int c   = col & 1023;
                const int h   = c >> 6, dh = c & 63;
                const float* bp = (mat == 0) ? b0 : ((mat == 1) ? b1 : b2);
                const float bv = bp[c];
#pragma unroll
                for (int r = 0; r < 4; r++) {
                    const int row = m0 + wr*(BM/2) + mf*16 + lg*4 + r;
                    const int b = row >> 11, s = row & 2047;
                    float v = acc[mf][nf][r] + bv;
                    if (mat == 0) {
                        v *= SL2E_F;             // fold attn scale+log2e into Q
                        ((ushort_t*)out0)[((size_t)(b*NHEAD + h) * S_LEN + s) * DHEAD + dh] = f2bf(v);
                    } else if (mat == 1)
                        ((ushort_t*)out1)[((size_t)(b*NHEAD + h) * S_LEN + s) * DHEAD + dh] = f2bf(v);
                    else
                        ((ushort_t*)out2)[((size_t)(b*NHEAD + h) * DHEAD + dh) * S_LEN + s] = f2bf(v);
                }
            }
        }
    }
}

// Flash attention, causal. One 64-row q-tile per block, swapped QK^T,
// double-buffered K/V with counted vmcnt + raw barriers, defer-max,
// diagonal-only mask, exp2 domain (Q pre-scaled).
__launch_bounds__(256, 4)
__global__ void attn_fwd(const ushort_t* __restrict__ Q, const ushort_t* __restrict__ Kh,
                         const ushort_t* __restrict__ Vt, ushort_t* __restrict__ Aout) {
    __shared__ ushort_t Ks[2][64][64];
    __shared__ ushort_t Vs[2][64][64];       // [dh][kv]
    __shared__ ushort_t Ps[4][16][64];       // XOR-swizzled, per-wave
    const int tid  = threadIdx.x;
    const int lane = tid & 63;
    const int w    = tid >> 6;
    const int l15  = lane & 15, lg = lane >> 4;
    const int bh   = blockIdx.x;
    const int y    = blockIdx.y;
    const int kq   = y >> 3, g0 = y & 7;
    const int qt   = (kq == 0) ? 2*g0 : (kq == 1) ? (31 - 2*g0)
                   : (kq == 2) ? (2*g0 + 1) : (30 - 2*g0);

    const size_t qkbase = (size_t)bh * S_LEN * DHEAD;
    const size_t vtbase = (size_t)bh * DHEAD * S_LEN;

    const int rsub  = lane >> 3;
    const int csw   = ((lane & 7) ^ rsub) * 8;
    const int swz   = (l15 & 7) * 8;
    const int psxor = (l15 & 7) << 4;

    const int qw = qt * 64 + w * 16;

    bf16x8 aq[2];
#pragma unroll
    for (int kc = 0; kc < 2; kc++)
        aq[kc] = *(const bf16x8*)(Q + qkbase + (size_t)(qw + l15) * DHEAD + kc*32 + lg*8);

    float m = -3.0e38f, l = 0.0f;
    f32x4 o[4] = {};

    auto stage = [&](int buf, int t) {
        const int kv0 = t * 64;
        const ushort_t* kp = Kh + qkbase + (size_t)kv0 * DHEAD;
        const ushort_t* vp = Vt + vtbase + kv0;
#pragma unroll
        for (int j2 = 0; j2 < 2; j2++) {
            const int j  = w * 2 + j2;
            const int rg = j * 8 + rsub;
            gload16(kp + (size_t)rg * DHEAD + csw, &Ks[buf][j*8][0]);
            gload16(vp + (size_t)rg * S_LEN + csw, &Vs[buf][j*8][0]);
        }
    };

    ushort_t* psw = &Ps[w][0][0];
    char* psrow = (char*)(psw + l15 * 64);

    stage(0, 0);
    int buf = 0;

    for (int t = 0; t <= qt; t++) {
        if (t < qt) {
            stage(buf ^ 1, t + 1);
            wait_vmcnt<4>();
        } else {
            wait_vmcnt<0>();
        }
        __builtin_amdgcn_s_barrier();
        __builtin_amdgcn_sched_barrier(0);

        // S^T = K Q^T : row = kv = nf*16+lg*4+r, col = q = l15
        f32x4 sacc[4] = {};
        __builtin_amdgcn_s_setprio(1);
#pragma unroll
        for (int kc = 0; kc < 2; kc++)
#pragma unroll
            for (int nf = 0; nf < 4; nf++) {
                bf16x8 bk = *(const bf16x8*)&Ks[buf][nf*16 + l15][(kc*32 + lg*8) ^ swz];
                sacc[nf] = __builtin_amdgcn_mfma_f32_16x16x32_bf16(bk, aq[kc], sacc[nf], 0, 0, 0);
            }
        __builtin_amdgcn_s_setprio(0);

        if (t == qt) {                               // diagonal: causal mask
            const int rowq = qw + l15;
            const int kv0  = t * 64;
#pragma unroll
            for (int nf = 0; nf < 4; nf++)
#pragma unroll
                for (int r = 0; r < 4; r++) {
                    const int colk = kv0 + nf*16 + lg*4 + r;
                    if (colk > rowq) sacc[nf][r] = -3.0e38f;
                }
        }

        float mnf[4];
#pragma unroll
        for (int nf = 0; nf < 4; nf++)
            mnf[nf] = fmaxf(fmaxf(sacc[nf][0], sacc[nf][1]), fmaxf(sacc[nf][2], sacc[nf][3]));
        float mx = fmaxf(fmaxf(mnf[0], mnf[1]), fmaxf(mnf[2], mnf[3]));
        mx = fmaxf(mx, __shfl_xor(mx, 16));
        mx = fmaxf(mx, __shfl_xor(mx, 32));

        const bool skip = __all(mx <= m + 8.0f);     // defer-max
        const float mn = skip ? m : fmaxf(m, mx);

        float snf[4];
#pragma unroll
        for (int nf = 0; nf < 4; nf++) {
            const float p0 = exp2f(sacc[nf][0] - mn);
            const float p1 = exp2f(sacc[nf][1] - mn);
            const float p2 = exp2f(sacc[nf][2] - mn);
            const float p3 = exp2f(sacc[nf][3] - mn);
            uint2 pk;
            pk.x = cvtpk_bf16(p0, p1);
            pk.y = cvtpk_bf16(p2, p3);
            *(uint2*)(psrow + (((nf*16 + lg*4) * 2) ^ psxor)) = pk;
            snf[nf] = (p0 + p1) + (p2 + p3);
        }
        float s = (snf[0] + snf[1]) + (snf[2] + snf[3]);
        s += __shfl_xor(s, 16);
        s += __shfl_xor(s, 32);

        if (skip) {
            l += s;
        } else {
            const float corr = exp2f(m - mn);
            m = mn;
            l = l * corr + s;
            float cf[4];
#pragma unroll
            for (int r = 0; r < 4; r++) cf[r] = __shfl(corr, lg*4 + r);
#pragma unroll
            for (int nf = 0; nf < 4; nf++)
#pragma unroll
                for (int r = 0; r < 4; r++) o[nf][r] *= cf[r];
        }

        // O += P @ V
        __builtin_amdgcn_s_setprio(1);
#pragma unroll
        for (int kc = 0; kc < 2; kc++) {
            bf16x8 pa = *(const bf16x8*)(psrow + (((kc*32 + lg*8) * 2) ^ psxor));
#pragma unroll
            for (int nf = 0; nf < 4; nf++) {
                bf16x8 bv = *(const bf16x8*)&Vs[buf][nf*16 + l15][(kc*32 + lg*8) ^ swz];
                o[nf] = __builtin_amdgcn_mfma_f32_16x16x32_bf16(pa, bv, o[nf], 0, 0, 0);
            }
        }
        __builtin_amdgcn_s_setprio(0);

        asm volatile("s_waitcnt lgkmcnt(0)" ::: "memory");
        __builtin_amdgcn_sched_barrier(0);
        __builtin_amdgcn_s_barrier();
        buf ^= 1;
    }

    // epilogue: O /= l (per q-row via shuffle), merge heads
    const int b = bh >> 4, h = bh & 15;
    const float inv = 1.0f / l;
#pragma unroll
    for (int r = 0; r < 4; r++) {
        const float ia = __shfl(inv, lg*4 + r);
        const int rowq = qw + lg*4 + r;
#pragma unroll
        for (int nf = 0; nf < 4; nf++)
            Aout[((size_t)(b * S_LEN) + rowq) * DMODEL + h*DHEAD + nf*16 + l15] = f2bf(o[nf][r] * ia);
    }
}

extern "C" void kernel_launch(void* const* d_in, const int* in_sizes, int n_in,
                              void* d_out, int out_size, void* d_ws, size_t ws_size,
                              hipStream_t stream) {
    (void)in_sizes; (void)n_in; (void)out_size; (void)ws_size;
    const float* x  = (const float*)d_in[0];
    const float* Wq = (const float*)d_in[2];
    const float* bq = (const float*)d_in[3];
    const float* Wk = (const float*)d_in[4];
    const float* bk = (const float*)d_in[5];
    const float* Wv = (const float*)d_in[6];
    const float* bv = (const float*)d_in[7];
    const float* Wo = (const float*)d_in[8];
    const float* bo = (const float*)d_in[9];

    char* ws = (char*)d_ws;
    ushort_t* xb    = (ushort_t*)(ws);                 // 4096x1024 bf16  (8 MB)
    ushort_t* Wqkvb = (ushort_t*)(ws + (8u  << 20));   // 3072x1024 bf16  (6 MB)
    ushort_t* Wob   = (ushort_t*)(ws + (14u << 20));   // 1024x1024 bf16  (2 MB)
    ushort_t* Qh    = (ushort_t*)(ws + (16u << 20));   // [B][H][S][DH]   (8 MB)
    ushort_t* Kh    = (ushort_t*)(ws + (24u << 20));   // [B][H][S][DH]   (8 MB)
    ushort_t* Vth   = (ushort_t*)(ws + (32u << 20));   // [B][H][DH][S]   (8 MB)
    ushort_t* Ao    = (ushort_t*)(ws + (40u << 20));   // [B][S][D] bf16  (8 MB)

    cast_all<<<2048, 256, 0, stream>>>(x, Wq, Wk, Wv, Wo, xb, 2097152);

    gemm_bt<0, 128><<<dim3(32, 24), 256, 0, stream>>>(xb, Wqkvb, bq, bk, bv,
                                                      Qh, Kh, Vth, 2*S_LEN, 3*DMODEL, DMODEL);

    attn_fwd<<<dim3(2*NHEAD, 32), 256, 0, stream>>>(Qh, Kh, Vth, Ao);

    gemm_bt<2, 64><<<dim3(64, 8), 256, 0, stream>>>(Ao, Wob, bo, nullptr, nullptr,
                                                    d_out, nullptr, nullptr, 2*S_LEN, DMODEL, DMODEL);
}

// Round 9
// 115.476 us; speedup vs baseline: 1.0472x; 1.0472x over previous
//
#include <hip/hip_runtime.h>

#define S_LEN  2048
#define DMODEL 1024
#define NHEAD  16
#define DHEAD  64
#define SCALE_F 0.125f
#define SL2E_F 0.180336880f   // SCALE_F * log2(e)

typedef unsigned short ushort_t;
typedef __attribute__((ext_vector_type(8))) short bf16x8;
typedef __attribute__((ext_vector_type(4))) float f32x4;

typedef __attribute__((address_space(1))) void gv_t;
typedef __attribute__((address_space(3))) void lv_t;

__device__ __forceinline__ ushort_t f2bf(float f) {
    unsigned u = __builtin_bit_cast(unsigned, f);
    unsigned r = (u + 0x7FFFu + ((u >> 16) & 1u)) >> 16;
    return (ushort_t)r;
}

__device__ __forceinline__ unsigned cvtpk_bf16(float a, float b) {
    unsigned r;
    asm("v_cvt_pk_bf16_f32 %0, %1, %2" : "=v"(r) : "v"(a), "v"(b));
    return r;
}

__device__ __forceinline__ void gload16(const ushort_t* g, ushort_t* l) {
    __builtin_amdgcn_global_load_lds((gv_t*)g, (lv_t*)l, 16, 0, 0);
}

template<int N> __device__ __forceinline__ void wait_vmcnt() {
    if constexpr (N == 8)      asm volatile("s_waitcnt vmcnt(8)" ::: "memory");
    else if constexpr (N == 6) asm volatile("s_waitcnt vmcnt(6)" ::: "memory");
    else if constexpr (N == 4) asm volatile("s_waitcnt vmcnt(4)" ::: "memory");
    else if constexpr (N == 3) asm volatile("s_waitcnt vmcnt(3)" ::: "memory");
    else                       asm volatile("s_waitcnt vmcnt(0)" ::: "memory");
}

// Cast x, Wq, Wk, Wv, Wo (f32) into one contiguous bf16 region.
__global__ void cast_all(const float* __restrict__ x,
                         const float* __restrict__ Wq, const float* __restrict__ Wk,
                         const float* __restrict__ Wv, const float* __restrict__ Wo,
                         ushort_t* __restrict__ dst, int n4) {
    int i = blockIdx.x * blockDim.x + threadIdx.x;
    int stride = gridDim.x * blockDim.x;
    for (int idx = i; idx < n4; idx += stride) {
        const float* src; int off;
        if (idx < 1048576)      { src = x;  off = idx; }
        else if (idx < 1310720) { src = Wq; off = idx - 1048576; }
        else if (idx < 1572864) { src = Wk; off = idx - 1310720; }
        else if (idx < 1835008) { src = Wv; off = idx - 1572864; }
        else                    { src = Wo; off = idx - 1835008; }
        float4 f = ((const float4*)src)[off];
        ushort4 o;
        o.x = f2bf(f.x); o.y = f2bf(f.y); o.z = f2bf(f.z); o.w = f2bf(f.w);
        ((ushort4*)dst)[idx] = o;
    }
}

// C = A @ B^T + bias.  BK=32 (32KB LDS dbuf), counted-vmcnt 2-deep pipeline
// (loads stay in flight across barriers), 16B-chunk XOR swizzle (2-way = free):
// stored_chunk = logical_chunk ^ ((row>>1)&3), applied source-side + read-side.
// MODE 0 (BM=128): fused QKV epilogue, N=3072; Q scaled by SL2E.
// MODE 2 (BM=64): out0 = f32 flat [M][N].
template<int MODE, int BM>
__launch_bounds__(256)
__global__ void gemm_bt(const ushort_t* __restrict__ A, const ushort_t* __restrict__ Bw,
                        const float* __restrict__ b0, const float* __restrict__ b1,
                        const float* __restrict__ b2,
                        void* __restrict__ out0, void* __restrict__ out1, void* __restrict__ out2,
                        int M, int N, int K) {
    constexpr int MF = BM / 32;
    constexpr int NLOADS = BM / 64 + 2;          // per-wave gloads per K-step
    __shared__ ushort_t As[2][BM][32];
    __shared__ ushort_t Bs[2][128][32];
    const int tid  = threadIdx.x;
    const int lane = tid & 63;
    const int w    = tid >> 6;
    const int wr   = w >> 1, wc = w & 1;
    const int m0   = blockIdx.x * BM;
    const int n0   = blockIdx.y * 128;
    const int l15  = lane & 15;
    const int lg   = lane >> 4;
    const int srow = lane >> 2;                  // 0..15: row within 16-row chunk
    const int scol = ((lane & 3) ^ ((lane >> 3) & 3)) * 8;  // swizzled source col
    const int ck   = (l15 >> 1) & 3;             // read-side chunk XOR

    f32x4 acc[MF][4] = {};

    auto stage = [&](int buf, int k0) {
#pragma unroll
        for (int j = 0; j < BM / 64; j++) {      // A: BM/16 instrs over 4 waves
            const int rg = (w * (BM / 64) + j) * 16;
            gload16(A + (size_t)(m0 + rg + srow) * K + k0 + scol, &As[buf][rg][0]);
        }
#pragma unroll
        for (int j = 0; j < 2; j++) {            // B: 8 instrs over 4 waves
            const int rg = (w * 2 + j) * 16;
            gload16(Bw + (size_t)(n0 + rg + srow) * K + k0 + scol, &Bs[buf][rg][0]);
        }
    };

    stage(0, 0);
    int buf = 0;

    for (int k0 = 0; k0 < K; k0 += 32) {
        if (k0 + 32 < K) {
            stage(buf ^ 1, k0 + 32);             // prefetch next tile
            wait_vmcnt<NLOADS>();                // current tile landed; prefetch in flight
        } else {
            wait_vmcnt<0>();
        }
        __builtin_amdgcn_s_barrier();
        __builtin_amdgcn_sched_barrier(0);

        bf16x8 af[MF], bfr[4];
#pragma unroll
        for (int i = 0; i < MF; i++)
            af[i]  = *(const bf16x8*)&As[buf][wr*(BM/2) + i*16 + l15][(lg ^ ck) * 8];
#pragma unroll
        for (int i = 0; i < 4;  i++)
            bfr[i] = *(const bf16x8*)&Bs[buf][wc*64 + i*16 + l15][(lg ^ ck) * 8];

        __builtin_amdgcn_s_setprio(1);
#pragma unroll
        for (int mf = 0; mf < MF; mf++)
#pragma unroll
            for (int nf = 0; nf < 4; nf++)
                acc[mf][nf] = __builtin_amdgcn_mfma_f32_16x16x32_bf16(af[mf], bfr[nf], acc[mf][nf], 0, 0, 0);
        __builtin_amdgcn_s_setprio(0);

        asm volatile("s_waitcnt lgkmcnt(0)" ::: "memory");
        __builtin_amdgcn_sched_barrier(0);
        __builtin_amdgcn_s_barrier();            // all waves done reading buf
        buf ^= 1;
    }

#pragma unroll
    for (int mf = 0; mf < MF; mf++) {
#pragma unroll
        for (int nf = 0; nf < 4; nf++) {
            const int col = n0 + wc*64 + nf*16 + l15;
            if constexpr (MODE == 2) {
                const float bv = b0[col];
#pragma unroll
                for (int r = 0; r < 4; r++) {
                    const int row = m0 + wr*(BM/2) + mf*16 + lg*4 + r;
                    ((float*)out0)[(size_t)row * N + col] = acc[mf][nf][r] + bv;
                }
            } else {
                const int mat = col >> 10;
                const int c   = col & 1023;
                const int h   = c >> 6, dh = c & 63;
                const float* bp = (mat == 0) ? b0 : ((mat == 1) ? b1 : b2);
                const float bv = bp[c];
#pragma unroll
                for (int r = 0; r < 4; r++) {
                    const int row = m0 + wr*(BM/2) + mf*16 + lg*4 + r;
                    const int b = row >> 11, s = row & 2047;
                    float v = acc[mf][nf][r] + bv;
                    if (mat == 0) {
                        v *= SL2E_F;             // fold attn scale+log2e into Q
                        ((ushort_t*)out0)[((size_t)(b*NHEAD + h) * S_LEN + s) * DHEAD + dh] = f2bf(v);
                    } else if (mat == 1)
                        ((ushort_t*)out1)[((size_t)(b*NHEAD + h) * S_LEN + s) * DHEAD + dh] = f2bf(v);
                    else
                        ((ushort_t*)out2)[((size_t)(b*NHEAD + h) * DHEAD + dh) * S_LEN + s] = f2bf(v);
                }
            }
        }
    }
}

// Flash attention, causal. One 64-row q-tile per block, swapped QK^T,
// double-buffered K/V with counted vmcnt + raw barriers, defer-max,
// diagonal-only mask, exp2 domain (Q pre-scaled).
__launch_bounds__(256, 4)
__global__ void attn_fwd(const ushort_t* __restrict__ Q, const ushort_t* __restrict__ Kh,
                         const ushort_t* __restrict__ Vt, ushort_t* __restrict__ Aout) {
    __shared__ ushort_t Ks[2][64][64];
    __shared__ ushort_t Vs[2][64][64];       // [dh][kv]
    __shared__ ushort_t Ps[4][16][64];       // XOR-swizzled, per-wave
    const int tid  = threadIdx.x;
    const int lane = tid & 63;
    const int w    = tid >> 6;
    const int l15  = lane & 15, lg = lane >> 4;
    const int bh   = blockIdx.x;
    const int y    = blockIdx.y;
    const int kq   = y >> 3, g0 = y & 7;
    const int qt   = (kq == 0) ? 2*g0 : (kq == 1) ? (31 - 2*g0)
                   : (kq == 2) ? (2*g0 + 1) : (30 - 2*g0);

    const size_t qkbase = (size_t)bh * S_LEN * DHEAD;
    const size_t vtbase = (size_t)bh * DHEAD * S_LEN;

    const int rsub  = lane >> 3;
    const int csw   = ((lane & 7) ^ rsub) * 8;
    const int swz   = (l15 & 7) * 8;
    const int psxor = (l15 & 7) << 4;

    const int qw = qt * 64 + w * 16;

    bf16x8 aq[2];
#pragma unroll
    for (int kc = 0; kc < 2; kc++)
        aq[kc] = *(const bf16x8*)(Q + qkbase + (size_t)(qw + l15) * DHEAD + kc*32 + lg*8);

    float m = -3.0e38f, l = 0.0f;
    f32x4 o[4] = {};

    auto stage = [&](int buf, int t) {
        const int kv0 = t * 64;
        const ushort_t* kp = Kh + qkbase + (size_t)kv0 * DHEAD;
        const ushort_t* vp = Vt + vtbase + kv0;
#pragma unroll
        for (int j2 = 0; j2 < 2; j2++) {
            const int j  = w * 2 + j2;
            const int rg = j * 8 + rsub;
            gload16(kp + (size_t)rg * DHEAD + csw, &Ks[buf][j*8][0]);
            gload16(vp + (size_t)rg * S_LEN + csw, &Vs[buf][j*8][0]);
        }
    };

    ushort_t* psw = &Ps[w][0][0];
    char* psrow = (char*)(psw + l15 * 64);

    stage(0, 0);
    int buf = 0;

    for (int t = 0; t <= qt; t++) {
        if (t < qt) {
            stage(buf ^ 1, t + 1);
            wait_vmcnt<4>();
        } else {
            wait_vmcnt<0>();
        }
        __builtin_amdgcn_s_barrier();
        __builtin_amdgcn_sched_barrier(0);

        // S^T = K Q^T : row = kv = nf*16+lg*4+r, col = q = l15
        f32x4 sacc[4] = {};
        __builtin_amdgcn_s_setprio(1);
#pragma unroll
        for (int kc = 0; kc < 2; kc++)
#pragma unroll
            for (int nf = 0; nf < 4; nf++) {
                bf16x8 bk = *(const bf16x8*)&Ks[buf][nf*16 + l15][(kc*32 + lg*8) ^ swz];
                sacc[nf] = __builtin_amdgcn_mfma_f32_16x16x32_bf16(bk, aq[kc], sacc[nf], 0, 0, 0);
            }
        __builtin_amdgcn_s_setprio(0);

        if (t == qt) {                               // diagonal: causal mask
            const int rowq = qw + l15;
            const int kv0  = t * 64;
#pragma unroll
            for (int nf = 0; nf < 4; nf++)
#pragma unroll
                for (int r = 0; r < 4; r++) {
                    const int colk = kv0 + nf*16 + lg*4 + r;
                    if (colk > rowq) sacc[nf][r] = -3.0e38f;
                }
        }

        float mnf[4];
#pragma unroll
        for (int nf = 0; nf < 4; nf++)
            mnf[nf] = fmaxf(fmaxf(sacc[nf][0], sacc[nf][1]), fmaxf(sacc[nf][2], sacc[nf][3]));
        float mx = fmaxf(fmaxf(mnf[0], mnf[1]), fmaxf(mnf[2], mnf[3]));
        mx = fmaxf(mx, __shfl_xor(mx, 16));
        mx = fmaxf(mx, __shfl_xor(mx, 32));

        const bool skip = __all(mx <= m + 8.0f);     // defer-max
        const float mn = skip ? m : fmaxf(m, mx);

        float snf[4];
#pragma unroll
        for (int nf = 0; nf < 4; nf++) {
            const float p0 = exp2f(sacc[nf][0] - mn);
            const float p1 = exp2f(sacc[nf][1] - mn);
            const float p2 = exp2f(sacc[nf][2] - mn);
            const float p3 = exp2f(sacc[nf][3] - mn);
            uint2 pk;
            pk.x = cvtpk_bf16(p0, p1);
            pk.y = cvtpk_bf16(p2, p3);
            *(uint2*)(psrow + (((nf*16 + lg*4) * 2) ^ psxor)) = pk;
            snf[nf] = (p0 + p1) + (p2 + p3);
        }
        float s = (snf[0] + snf[1]) + (snf[2] + snf[3]);
        s += __shfl_xor(s, 16);
        s += __shfl_xor(s, 32);

        if (skip) {
            l += s;
        } else {
            const float corr = exp2f(m - mn);
            m = mn;
            l = l * corr + s;
            float cf[4];
#pragma unroll
            for (int r = 0; r < 4; r++) cf[r] = __shfl(corr, lg*4 + r);
#pragma unroll
            for (int nf = 0; nf < 4; nf++)
#pragma unroll
                for (int r = 0; r < 4; r++) o[nf][r] *= cf[r];
        }

        // O += P @ V
        __builtin_amdgcn_s_setprio(1);
#pragma unroll
        for (int kc = 0; kc < 2; kc++) {
            bf16x8 pa = *(const bf16x8*)(psrow + (((kc*32 + lg*8) * 2) ^ psxor));
#pragma unroll
            for (int nf = 0; nf < 4; nf++) {
                bf16x8 bv = *(const bf16x8*)&Vs[buf][nf*16 + l15][(kc*32 + lg*8) ^ swz];
                o[nf] = __builtin_amdgcn_mfma_f32_16x16x32_bf16(pa, bv, o[nf], 0, 0, 0);
            }
        }
        __builtin_amdgcn_s_setprio(0);

        asm volatile("s_waitcnt lgkmcnt(0)" ::: "memory");
        __builtin_amdgcn_sched_barrier(0);
        __builtin_amdgcn_s_barrier();
        buf ^= 1;
    }

    // epilogue: O /= l (per q-row via shuffle), merge heads
    const int b = bh >> 4, h = bh & 15;
    const float inv = 1.0f / l;
#pragma unroll
    for (int r = 0; r < 4; r++) {
        const float ia = __shfl(inv, lg*4 + r);
        const int rowq = qw + lg*4 + r;
#pragma unroll
        for (int nf = 0; nf < 4; nf++)
            Aout[((size_t)(b * S_LEN) + rowq) * DMODEL + h*DHEAD + nf*16 + l15] = f2bf(o[nf][r] * ia);
    }
}

extern "C" void kernel_launch(void* const* d_in, const int* in_sizes, int n_in,
                              void* d_out, int out_size, void* d_ws, size_t ws_size,
                              hipStream_t stream) {
    (void)in_sizes; (void)n_in; (void)out_size; (void)ws_size;
    const float* x  = (const float*)d_in[0];
    const float* Wq = (const float*)d_in[2];
    const float* bq = (const float*)d_in[3];
    const float* Wk = (const float*)d_in[4];
    const float* bk = (const float*)d_in[5];
    const float* Wv = (const float*)d_in[6];
    const float* bv = (const float*)d_in[7];
    const float* Wo = (const float*)d_in[8];
    const float* bo = (const float*)d_in[9];

    char* ws = (char*)d_ws;
    ushort_t* xb    = (ushort_t*)(ws);                 // 4096x1024 bf16  (8 MB)
    ushort_t* Wqkvb = (ushort_t*)(ws + (8u  << 20));   // 3072x1024 bf16  (6 MB)
    ushort_t* Wob   = (ushort_t*)(ws + (14u << 20));   // 1024x1024 bf16  (2 MB)
    ushort_t* Qh    = (ushort_t*)(ws + (16u << 20));   // [B][H][S][DH]   (8 MB)
    ushort_t* Kh    = (ushort_t*)(ws + (24u << 20));   // [B][H][S][DH]   (8 MB)
    ushort_t* Vth   = (ushort_t*)(ws + (32u << 20));   // [B][H][DH][S]   (8 MB)
    ushort_t* Ao    = (ushort_t*)(ws + (40u << 20));   // [B][S][D] bf16  (8 MB)

    cast_all<<<2048, 256, 0, stream>>>(x, Wq, Wk, Wv, Wo, xb, 2097152);

    gemm_bt<0, 128><<<dim3(32, 24), 256, 0, stream>>>(xb, Wqkvb, bq, bk, bv,
                                                      Qh, Kh, Vth, 2*S_LEN, 3*DMODEL, DMODEL);

    attn_fwd<<<dim3(2*NHEAD, 32), 256, 0, stream>>>(Qh, Kh, Vth, Ao);

    gemm_bt<2, 64><<<dim3(64, 8), 256, 0, stream>>>(Ao, Wob, bo, nullptr, nullptr,
                                                    d_out, nullptr, nullptr, 2*S_LEN, DMODEL, DMODEL);
}